// Round 5
// baseline (191.331 us; speedup 1.0000x reference)
//
#include <hip/hip_runtime.h>

// AdderNet 2D: out[n,co,ho,wo] = -sum_{ci,kh,kw} |x_pad - w|
// x: [16,64,56,56] f32, w: [64,64,3,3] f32, out: [16,64,56,56] f32.
// VALU floor ~47 us. R4 analysis: real VALU busy ~37% (gfx94x formula halves
// on SIMD-32); idle from low residency (3 blk/CU) + LDS broadcast pressure.
//
// R5: 512-thr blocks (8 waves), tile 8x8. wave = (row-group g of 4 rows) x
// (ci-quarter q of 16). lane = co. R=4 rows/wave: 18 broadcast ds_reads per
// 576 VALU-instr per ci (ratio 0.75 vs R4's 1.0). 4-way ci merge in LDS.
// 48 KiB LDS -> 3 blocks/CU = 24 waves/CU even under the R4 residency cap.

#define NCI   64
#define LDSW  12   // padded row stride: rows 48B apart -> every row 16B-aligned

// pre-kernel: w[co][ci][k] -> wt[ci][k4][co][4]  (k = k4*4+jj, k>=9 zero-pad)
__global__ void wt_transpose_kernel(const float* __restrict__ w, float* __restrict__ wt) {
    int idx = blockIdx.x * 256 + threadIdx.x;   // 64*3*64*4 = 49152
    if (idx >= NCI * 3 * 64 * 4) return;
    int ci  = idx / 768;
    int rem = idx % 768;
    int k4  = rem / 256;
    int r2  = rem % 256;
    int co  = r2 / 4;
    int jj  = r2 % 4;
    int k   = k4 * 4 + jj;
    wt[idx] = (k < 9) ? w[(co * NCI + ci) * 9 + k] : 0.0f;
}

// one x-row (12 floats incl. 2 pad) -> xr[], as 3 aligned b128 reads
#define LOADROW12(xr, base)                                 \
    {                                                       \
        float4 A = *(const float4*)(base);                  \
        float4 B = *(const float4*)((base) + 4);            \
        float4 Cq = *(const float4*)((base) + 8);           \
        xr[0]=A.x;  xr[1]=A.y;  xr[2]=A.z;  xr[3]=A.w;      \
        xr[4]=B.x;  xr[5]=B.y;  xr[6]=B.z;  xr[7]=B.w;      \
        xr[8]=Cq.x; xr[9]=Cq.y;                             \
    }

#define TAPS(i, kh)                                         \
    _Pragma("unroll")                                       \
    for (int kw = 0; kw < 3; ++kw) {                        \
        const float wv_ = wreg[(kh)*3 + kw];                \
        _Pragma("unroll")                                   \
        for (int s = 0; s < 8; ++s)                         \
            acc[i][s] += fabsf(xr[s + kw] - wv_);           \
    }

template <bool USE_WT>
__global__ __launch_bounds__(512, 6) void adder2d_main(
    const float* __restrict__ x, const float* __restrict__ w,
    const float* __restrict__ wt, float* __restrict__ out)
{
    // 48 KiB: x slab [64][10][LDSW] = 7680 f, overlaid by merge buf [6][2048]
    __shared__ float lds[12288];

    const int bid = blockIdx.x;
    const int n   = bid / 49;          // 7x7 tiles of 8x8 per image
    const int t   = bid % 49;
    const int r0  = (t / 7) * 8;
    const int c0  = (t % 7) * 8;

    const int tid  = threadIdx.x;
    const int lane = tid & 63;         // = co
    const int wv   = tid >> 6;         // 0..7
    const int g    = wv & 1;           // row group: rows r0+4g .. r0+4g+3
    const int q    = wv >> 1;          // ci quarter: ci q*16 .. q*16+15

    // ---- stage x: rows r0-1..r0+8 (10), cols c0-1..c0+8 (10), all ci ----
    const float* xn = x + (size_t)n * NCI * 56 * 56;
    for (int idx = tid; idx < NCI * 10 * 10; idx += 512) {
        int ci  = idx / 100;
        int rem = idx % 100;
        int r   = rem / 10;
        int c   = rem % 10;
        int gh  = r0 + r - 1;
        int gw  = c0 + c - 1;
        float v = 0.f;
        if ((unsigned)gh < 56u && (unsigned)gw < 56u)
            v = xn[(ci * 56 + gh) * 56 + gw];
        lds[(ci * 10 + r) * LDSW + c] = v;
    }
    __syncthreads();

    float acc[4][8];
    #pragma unroll
    for (int i = 0; i < 4; ++i)
        #pragma unroll
        for (int s = 0; s < 8; ++s) acc[i][s] = 0.f;

    const float4* wt4 = (const float4*)wt;
    const int ci0 = q * 16;

    for (int ci = ci0; ci < ci0 + 16; ++ci) {
        float wreg[12];
        if (USE_WT) {
            #pragma unroll
            for (int k4 = 0; k4 < 3; ++k4) {
                float4 qv = wt4[(ci * 3 + k4) * 64 + lane];
                wreg[k4*4+0] = qv.x; wreg[k4*4+1] = qv.y;
                wreg[k4*4+2] = qv.z; wreg[k4*4+3] = qv.w;
            }
        } else {
            #pragma unroll
            for (int k = 0; k < 9; ++k)
                wreg[k] = w[(lane * NCI + ci) * 9 + k];
        }

        const float* slab = &lds[(ci * 10 + g * 4) * LDSW];

        // stream 6 x-rows; row j feeds acc[i] for i=j-2..j with kh=j-i
        { float xr[10]; LOADROW12(xr, slab);            TAPS(0,0) }
        { float xr[10]; LOADROW12(xr, slab + 1*LDSW);   TAPS(0,1) TAPS(1,0) }
        { float xr[10]; LOADROW12(xr, slab + 2*LDSW);   TAPS(0,2) TAPS(1,1) TAPS(2,0) }
        { float xr[10]; LOADROW12(xr, slab + 3*LDSW);   TAPS(1,2) TAPS(2,1) TAPS(3,0) }
        { float xr[10]; LOADROW12(xr, slab + 4*LDSW);   TAPS(2,2) TAPS(3,1) }
        { float xr[10]; LOADROW12(xr, slab + 5*LDSW);   TAPS(3,2) }
    }

    // ---- 4-way ci merge: red[(q-1)*2+g][i*8+s][lane] ----
    __syncthreads();   // all x reads done; overlay safe
    if (q != 0) {
        float* red = &lds[((q - 1) * 2 + g) * 2048];
        #pragma unroll
        for (int i = 0; i < 4; ++i)
            #pragma unroll
            for (int s = 0; s < 8; ++s)
                red[(i * 8 + s) * 64 + lane] = acc[i][s];
    }
    __syncthreads();
    if (q == 0) {
        #pragma unroll
        for (int qq = 1; qq <= 3; ++qq) {
            const float* red = &lds[((qq - 1) * 2 + g) * 2048];
            #pragma unroll
            for (int i = 0; i < 4; ++i)
                #pragma unroll
                for (int s = 0; s < 8; ++s)
                    acc[i][s] += red[(i * 8 + s) * 64 + lane];
        }
        float* op = out + (((size_t)n * 64 + lane) * 56 + (r0 + g * 4)) * 56 + c0;
        #pragma unroll
        for (int i = 0; i < 4; ++i) {
            *(float4*)(op + i * 56)     = make_float4(-acc[i][0], -acc[i][1], -acc[i][2], -acc[i][3]);
            *(float4*)(op + i * 56 + 4) = make_float4(-acc[i][4], -acc[i][5], -acc[i][6], -acc[i][7]);
        }
    }
}

extern "C" void kernel_launch(void* const* d_in, const int* in_sizes, int n_in,
                              void* d_out, int out_size, void* d_ws, size_t ws_size,
                              hipStream_t stream) {
    const float* x = (const float*)d_in[0];
    const float* w = (const float*)d_in[1];
    float* out = (float*)d_out;
    float* wt  = (float*)d_ws;

    const size_t wt_bytes = (size_t)NCI * 3 * 64 * 4 * sizeof(float);  // 192 KiB
    const bool use_wt = ws_size >= wt_bytes;

    if (use_wt) {
        wt_transpose_kernel<<<(NCI * 3 * 64 * 4 + 255) / 256, 256, 0, stream>>>(w, wt);
        adder2d_main<true><<<16 * 49, 512, 0, stream>>>(x, w, wt, out);
    } else {
        adder2d_main<false><<<16 * 49, 512, 0, stream>>>(x, w, wt, out);
    }
}

// Round 6
// 130.135 us; speedup vs baseline: 1.4703x; 1.4703x over previous
//
#include <hip/hip_runtime.h>

// AdderNet 2D: out[n,co,ho,wo] = -sum_{ci,kh,kw} |x_pad - w|
// x: [16,64,56,56] f32, w: [64,64,3,3] f32, out: [16,64,56,56] f32.
// VALU issue floor ~47 us @2.4GHz (2 instr per reduce elem: v_sub + v_add(abs)).
//
// R5 lessons: (a) compiler VGPR cap ~= 256/min_waves_arg -> (256,4) = 64 is
// the safe setting for this ~55-reg loop; (b) HW residency allows 8 waves/EU
// whenever VGPR<=64 (m69) -- launch_bounds doesn't gate it, the GRID does.
// R2/R4/R5 all fed only ~12 waves/CU. R6 fixes the grid: 3136 blocks
// (12.25/CU) so the 32-waves/CU cap is grid-fed.
//
// Structure: lane = co. Block = 256 thr = 4 waves = 4 ci-quarters.
// Tile = 2 rows x 8 cols. Wave: both rows, 16 ci, streaming 4 x-rows
// (broadcast b128 LDS reads), weights per-lane from transposed wt.
// 4-way ci merge via LDS overlay.

#define NCI   64
#define LDSW  12    // padded LDS row stride (48B): every row float4-aligned

// pre-kernel: w[co][ci][k] -> wt[ci][k4][co][4]  (k = k4*4+jj, k>=9 zero-pad)
__global__ void wt_transpose_kernel(const float* __restrict__ w, float* __restrict__ wt) {
    int idx = blockIdx.x * 256 + threadIdx.x;   // 64*3*64*4 = 49152
    if (idx >= NCI * 3 * 64 * 4) return;
    int ci  = idx / 768;
    int rem = idx % 768;
    int k4  = rem / 256;
    int r2  = rem % 256;
    int co  = r2 / 4;
    int jj  = r2 % 4;
    int k   = k4 * 4 + jj;
    wt[idx] = (k < 9) ? w[(co * NCI + ci) * 9 + k] : 0.0f;
}

#define LOADROW(xr, base)                                   \
    {                                                       \
        float4 A = *(const float4*)(base);                  \
        float4 B = *(const float4*)((base) + 4);            \
        float2 C = *(const float2*)((base) + 8);            \
        xr[0]=A.x; xr[1]=A.y; xr[2]=A.z; xr[3]=A.w;         \
        xr[4]=B.x; xr[5]=B.y; xr[6]=B.z; xr[7]=B.w;         \
        xr[8]=C.x; xr[9]=C.y;                               \
    }

#define TAPS(acc, xr, wreg, kh)                             \
    _Pragma("unroll")                                       \
    for (int kw = 0; kw < 3; ++kw) {                        \
        const float wv_ = wreg[(kh)*3 + kw];                \
        _Pragma("unroll")                                   \
        for (int s = 0; s < 8; ++s)                         \
            acc[s] += fabsf(xr[s + kw] - wv_);              \
    }

template <bool USE_WT>
__global__ __launch_bounds__(256, 4) void adder2d_main(
    const float* __restrict__ x, const float* __restrict__ w,
    const float* __restrict__ wt, float* __restrict__ out)
{
    // 12 KiB: x slab [64 ci][4 rows][LDSW], overlaid by merge buf [3][16][64]
    __shared__ float lds[NCI * 4 * LDSW];

    const int bid = blockIdx.x;
    const int n   = bid / 196;         // 28 row-tiles * 7 col-tiles
    const int t   = bid % 196;
    const int r0  = (t / 7) * 2;
    const int c0  = (t % 7) * 8;

    const int tid  = threadIdx.x;
    const int lane = tid & 63;         // = co
    const int q    = tid >> 6;         // ci quarter: ci q*16 .. q*16+15

    // ---- stage x: rows r0-1..r0+2 (4), cols c0-1..c0+8 (10), all ci ----
    const float* xn = x + (size_t)n * NCI * 56 * 56;
    #pragma unroll
    for (int it = 0; it < 10; ++it) {            // 2560 = 256*10 exactly
        int idx = it * 256 + tid;
        int ci  = idx / 40;
        int rem = idx % 40;
        int r   = rem / 10;
        int c   = rem % 10;
        int gh  = r0 + r - 1;
        int gw  = c0 + c - 1;
        float v = 0.f;
        if ((unsigned)gh < 56u && (unsigned)gw < 56u)
            v = xn[(ci * 56 + gh) * 56 + gw];
        lds[(ci * 4 + r) * LDSW + c] = v;
    }
    __syncthreads();

    float acc0[8], acc1[8];
    #pragma unroll
    for (int s = 0; s < 8; ++s) { acc0[s] = 0.f; acc1[s] = 0.f; }

    const float4* wt4 = (const float4*)wt;
    const int ci0 = q * 16;

    for (int ci = ci0; ci < ci0 + 16; ++ci) {
        float wreg[12];
        if (USE_WT) {
            #pragma unroll
            for (int k4 = 0; k4 < 3; ++k4) {
                float4 qv = wt4[(ci * 3 + k4) * 64 + lane];
                wreg[k4*4+0] = qv.x; wreg[k4*4+1] = qv.y;
                wreg[k4*4+2] = qv.z; wreg[k4*4+3] = qv.w;
            }
        } else {
            #pragma unroll
            for (int k = 0; k < 9; ++k)
                wreg[k] = w[(lane * NCI + ci) * 9 + k];
        }

        const float* rb = &lds[(ci * 4) * LDSW];

        // stream 4 x-rows; row j feeds acc0 (kh=j, j<=2) and acc1 (kh=j-1, j>=1)
        {
            float xr[10]; LOADROW(xr, rb);
            TAPS(acc0, xr, wreg, 0);
        }
        {
            float xr[10]; LOADROW(xr, rb + LDSW);
            TAPS(acc0, xr, wreg, 1);
            TAPS(acc1, xr, wreg, 0);
        }
        {
            float xr[10]; LOADROW(xr, rb + 2 * LDSW);
            TAPS(acc0, xr, wreg, 2);
            TAPS(acc1, xr, wreg, 1);
        }
        {
            float xr[10]; LOADROW(xr, rb + 3 * LDSW);
            TAPS(acc1, xr, wreg, 2);
        }
    }

    // ---- 4-way ci merge via LDS overlay: red[q-1][slot 0..15][lane] ----
    __syncthreads();   // all x reads done; overlay safe
    if (q != 0) {
        float* red = &lds[(q - 1) * 16 * 64];
        #pragma unroll
        for (int s = 0; s < 8; ++s) {
            red[(s    ) * 64 + lane] = acc0[s];
            red[(s + 8) * 64 + lane] = acc1[s];
        }
    }
    __syncthreads();
    if (q == 0) {
        #pragma unroll
        for (int qq = 0; qq < 3; ++qq) {
            const float* red = &lds[qq * 16 * 64];
            #pragma unroll
            for (int s = 0; s < 8; ++s) {
                acc0[s] += red[(s    ) * 64 + lane];
                acc1[s] += red[(s + 8) * 64 + lane];
            }
        }
        float* op = out + (((size_t)n * 64 + lane) * 56 + r0) * 56 + c0;
        *(float4*)(op)          = make_float4(-acc0[0], -acc0[1], -acc0[2], -acc0[3]);
        *(float4*)(op + 4)      = make_float4(-acc0[4], -acc0[5], -acc0[6], -acc0[7]);
        *(float4*)(op + 56)     = make_float4(-acc1[0], -acc1[1], -acc1[2], -acc1[3]);
        *(float4*)(op + 56 + 4) = make_float4(-acc1[4], -acc1[5], -acc1[6], -acc1[7]);
    }
}

extern "C" void kernel_launch(void* const* d_in, const int* in_sizes, int n_in,
                              void* d_out, int out_size, void* d_ws, size_t ws_size,
                              hipStream_t stream) {
    const float* x = (const float*)d_in[0];
    const float* w = (const float*)d_in[1];
    float* out = (float*)d_out;
    float* wt  = (float*)d_ws;

    const size_t wt_bytes = (size_t)NCI * 3 * 64 * 4 * sizeof(float);  // 192 KiB
    const bool use_wt = ws_size >= wt_bytes;

    if (use_wt) {
        wt_transpose_kernel<<<(NCI * 3 * 64 * 4 + 255) / 256, 256, 0, stream>>>(w, wt);
        adder2d_main<true><<<16 * 196, 256, 0, stream>>>(x, w, wt, out);
    } else {
        adder2d_main<false><<<16 * 196, 256, 0, stream>>>(x, w, wt, out);
    }
}